// Round 23
// baseline (100.928 us; speedup 1.0000x reference)
//
#include <hip/hip_runtime.h>
#include <hip/hip_bf16.h>

typedef __attribute__((ext_vector_type(8))) short short8;
typedef __attribute__((ext_vector_type(4))) float f32x4;
typedef __attribute__((ext_vector_type(4))) unsigned short ushort4v;
typedef unsigned short u16;
typedef unsigned int u32;

#define MFMA32(a, b, c) __builtin_amdgcn_mfma_f32_16x16x32_bf16((a), (b), (c), 0, 0, 0)

__device__ __forceinline__ u16 f2bf(float f) {
    __hip_bfloat16 h = __float2bfloat16(f);       // RNE; compiler can fuse pairs
    return *reinterpret_cast<u16*>(&h);
}
__device__ __forceinline__ u32 pack2(float a, float b) {
    return ((u32)f2bf(b) << 16) | (u32)f2bf(a);
}

// One 32-s chunk step for one tile — R16/R18-verified chunk body (fixed-base
// softmax exp(S/8), causal mask, dropout, bpermute PV). No conditionals.
__device__ __forceinline__ void tile_step(int c2, int t_my, int lr, int lg,
                                          const int* adr,
                                          const short8* qf,           // [2]
                                          const u16 (*lk)[72],
                                          const u16 (*lvT)[264],
                                          const float* mb,
                                          float& ls, f32x4* O)
{
    f32x4 md0 = *(const f32x4*)&mb[(size_t)t_my * 256 + 32 * c2 + 4 * lg];
    f32x4 md1 = *(const f32x4*)&mb[(size_t)t_my * 256 + 32 * c2 + 16 + 4 * lg];

    f32x4 S0, S1;
    {
        const u16* kr = &lk[16 * (2 * c2) + lr][0];
        short8 kf0 = *(const short8*)&kr[8 * lg];
        short8 kf1 = *(const short8*)&kr[32 + 8 * lg];
        f32x4 a = (f32x4){0.f, 0.f, 0.f, 0.f};
        a = MFMA32(kf0, qf[0], a);
        a = MFMA32(kf1, qf[1], a);
        S0 = a;
    }
    {
        const u16* kr = &lk[16 * (2 * c2 + 1) + lr][0];
        short8 kf0 = *(const short8*)&kr[8 * lg];
        short8 kf1 = *(const short8*)&kr[32 + 8 * lg];
        f32x4 a = (f32x4){0.f, 0.f, 0.f, 0.f};
        a = MFMA32(kf0, qf[0], a);
        a = MFMA32(kf1, qf[1], a);
        S1 = a;
    }

    #pragma unroll
    for (int j = 0; j < 4; ++j) {
        const int sg0 = 32 * c2 + 4 * lg + j;
        const int sg1 = sg0 + 16;
        float p0 = exp2f(S0[j] * 0.180336879f);
        float p1 = exp2f(S1[j] * 0.180336879f);
        p0 = (sg0 <= t_my) ? p0 : 0.f;
        p1 = (sg1 <= t_my) ? p1 : 0.f;
        ls += p0 + p1;
        S0[j] = (md0[j] >= 0.25f) ? p0 : 0.f;
        S1[j] = (md1[j] >= 0.25f) ? p1 : 0.f;
    }

    u32 pk0[2], pk1[2];
    pk0[0] = pack2(S0[0], S0[1]); pk0[1] = pack2(S0[2], S0[3]);
    pk1[0] = pack2(S1[0], S1[1]); pk1[1] = pack2(S1[2], S1[3]);
    union { u32 u[4]; short8 s; } pf;
    #pragma unroll
    for (int e = 0; e < 4; ++e) {
        u32 ca = (u32)__builtin_amdgcn_ds_bpermute(adr[e], (int)pk0[e & 1]);
        u32 cb = (u32)__builtin_amdgcn_ds_bpermute(adr[e], (int)pk1[e & 1]);
        pf.u[e] = (lg >> 1) ? cb : ca;
    }

    #pragma unroll
    for (int ht = 0; ht < 4; ++ht) {
        short8 vf = *(const short8*)&lvT[16 * ht + lr][32 * c2 + 8 * lg];
        O[ht] = MFMA32(vf, pf.s, O[ht]);
    }
}

// Dual-tile attention, branch-free (R18-verified).
__device__ __forceinline__ void attn_dual(int tA, int tB, int lr, int lg,
                                          const int* adr,
                                          const short8* qfA, const short8* qfB,
                                          const u16 (*lk)[72],
                                          const u16 (*lvT)[264],
                                          const float* mb, float* ob)
{
    const int nchA = (tA + 2) >> 1;
    const int nchB = (tB + 2) >> 1;
    const int tmA  = 16 * tA + lr;
    const int tmB  = 16 * tB + lr;

    float lsA = 0.f, lsB = 0.f;
    f32x4 OA[4], OB[4];
    #pragma unroll
    for (int ht = 0; ht < 4; ++ht) {
        OA[ht] = (f32x4){0.f, 0.f, 0.f, 0.f};
        OB[ht] = (f32x4){0.f, 0.f, 0.f, 0.f};
    }

    int c2 = 0;
    for (; c2 < nchA; ++c2) {
        tile_step(c2, tmB, lr, lg, adr, qfB, lk, lvT, mb, lsB, OB);
        tile_step(c2, tmA, lr, lg, adr, qfA, lk, lvT, mb, lsA, OA);
    }
    for (; c2 < nchB; ++c2)
        tile_step(c2, tmB, lr, lg, adr, qfB, lk, lvT, mb, lsB, OB);

    lsA += __shfl_xor(lsA, 16, 64);
    lsA += __shfl_xor(lsA, 32, 64);
    lsB += __shfl_xor(lsB, 16, 64);
    lsB += __shfl_xor(lsB, 32, 64);

    const float rfA = 1.33333333333f / lsA;   // (1/sum) * 1/(1-0.25)
    const float rfB = 1.33333333333f / lsB;
    #pragma unroll
    for (int ht = 0; ht < 4; ++ht) {
        f32x4 oa  = OA[ht] * rfA;
        f32x4 obv = OB[ht] * rfB;
        *(f32x4*)&ob[(size_t)tmA * 64 + 16 * ht + 4 * lg] = oa;
        *(f32x4*)&ob[(size_t)tmB * 64 + 16 * ht + 4 * lg] = obv;
    }
}

// stage full W^T bf16 into wt: lane l owns row n=l; wave w owns chunks 8(w+8i)
#define STAGE_W(Wm) do {                                                     \
    _Pragma("unroll")                                                        \
    for (int i_ = 0; i_ < 4; ++i_) {                                         \
        const int c0_ = 8 * (w + 8 * i_);                                    \
        short8 t_;                                                           \
        _Pragma("unroll")                                                    \
        for (int j_ = 0; j_ < 8; ++j_)                                       \
            t_[j_] = (short)f2bf((Wm)[(size_t)(c0_ + j_) * 64 + l]);         \
        *(short8*)&wt[l][c0_] = t_;                                          \
    } } while (0)

// issue one tile's x rows into f32 registers (16 x f32x4, stay in flight)
#define ISSUE_X(dst, xb_, Tbase) do {                                        \
    const float* xr_ = (xb_) + (size_t)((Tbase) + lr) * 256 + lg * 8;        \
    _Pragma("unroll")                                                        \
    for (int ks_ = 0; ks_ < 8; ++ks_) {                                      \
        dst[2 * ks_]     = *(const f32x4*)(xr_ + ks_ * 32);                  \
        dst[2 * ks_ + 1] = *(const f32x4*)(xr_ + ks_ * 32 + 4);              \
    } } while (0)

// convert a prefetched x tile to bf16 A-fragments
#define CVT_X(af_, src) do {                                                 \
    _Pragma("unroll")                                                        \
    for (int ks_ = 0; ks_ < 8; ++ks_) {                                      \
        f32x4 a0_ = src[2 * ks_], a1_ = src[2 * ks_ + 1];                    \
        short8 f_;                                                           \
        f_[0] = (short)f2bf(a0_[0]); f_[1] = (short)f2bf(a0_[1]);            \
        f_[2] = (short)f2bf(a0_[2]); f_[3] = (short)f2bf(a0_[3]);            \
        f_[4] = (short)f2bf(a1_[0]); f_[5] = (short)f2bf(a1_[1]);            \
        f_[6] = (short)f2bf(a1_[2]); f_[7] = (short)f2bf(a1_[3]);            \
        (af_)[ks_] = f_;                                                     \
    } } while (0)

// full R18 projection phase: af[2][8] -> lk, lvT, qf (5 barriers)
#define DO_PROJ(qf_) do {                                                    \
    f32x4 acc[2][4];                                                         \
    STAGE_W(Wk);                                                             \
    __syncthreads();                                                         \
    _Pragma("unroll")                                                        \
    for (int ti = 0; ti < 2; ++ti)                                           \
        _Pragma("unroll")                                                    \
        for (int nj = 0; nj < 4; ++nj) acc[ti][nj] = (f32x4){0.f,0.f,0.f,0.f}; \
    _Pragma("unroll")                                                        \
    for (int ks = 0; ks < 8; ++ks)                                           \
        _Pragma("unroll")                                                    \
        for (int nj = 0; nj < 4; ++nj) {                                     \
            short8 bf = *(const short8*)&wt[16 * nj + lr][ks * 32 + lg * 8]; \
            acc[0][nj] = MFMA32(af[0][ks], bf, acc[0][nj]);                  \
            acc[1][nj] = MFMA32(af[1][ks], bf, acc[1][nj]);                  \
        }                                                                    \
    _Pragma("unroll")                                                        \
    for (int nj = 0; nj < 4; ++nj) {                                         \
        const int n = 16 * nj + lr;                                          \
        _Pragma("unroll")                                                    \
        for (int j = 0; j < 4; ++j) {                                        \
            lk[TbA + 4 * lg + j][n] = f2bf(acc[0][nj][j]);                   \
            lk[TbB + 4 * lg + j][n] = f2bf(acc[1][nj][j]);                   \
        }                                                                    \
    }                                                                        \
    __syncthreads();                                                         \
    STAGE_W(Wv);                                                             \
    __syncthreads();                                                         \
    _Pragma("unroll")                                                        \
    for (int ti = 0; ti < 2; ++ti)                                           \
        _Pragma("unroll")                                                    \
        for (int nj = 0; nj < 4; ++nj) acc[ti][nj] = (f32x4){0.f,0.f,0.f,0.f}; \
    _Pragma("unroll")                                                        \
    for (int ks = 0; ks < 8; ++ks)                                           \
        _Pragma("unroll")                                                    \
        for (int nj = 0; nj < 4; ++nj) {                                     \
            short8 bf = *(const short8*)&wt[16 * nj + lr][ks * 32 + lg * 8]; \
            acc[0][nj] = MFMA32(af[0][ks], bf, acc[0][nj]);                  \
            acc[1][nj] = MFMA32(af[1][ks], bf, acc[1][nj]);                  \
        }                                                                    \
    _Pragma("unroll")                                                        \
    for (int ti = 0; ti < 2; ++ti) {                                         \
        const int s0 = (ti ? TbB : TbA) + 4 * lg;                            \
        _Pragma("unroll")                                                    \
        for (int nj = 0; nj < 4; ++nj) {                                     \
            ushort4v pk;                                                     \
            pk[0] = f2bf(acc[ti][nj][0]);                                    \
            pk[1] = f2bf(acc[ti][nj][1]);                                    \
            pk[2] = f2bf(acc[ti][nj][2]);                                    \
            pk[3] = f2bf(acc[ti][nj][3]);                                    \
            *(ushort4v*)&lvT[16 * nj + lr][s0] = pk;                         \
        }                                                                    \
    }                                                                        \
    __syncthreads();                                                         \
    STAGE_W(Wq);                                                             \
    __syncthreads();                                                         \
    _Pragma("unroll")                                                        \
    for (int ti = 0; ti < 2; ++ti)                                           \
        _Pragma("unroll")                                                    \
        for (int nj = 0; nj < 4; ++nj) acc[ti][nj] = (f32x4){0.f,0.f,0.f,0.f}; \
    _Pragma("unroll")                                                        \
    for (int ks = 0; ks < 8; ++ks)                                           \
        _Pragma("unroll")                                                    \
        for (int nj = 0; nj < 4; ++nj) {                                     \
            short8 bf = *(const short8*)&wt[16 * nj + lr][ks * 32 + lg * 8]; \
            acc[0][nj] = MFMA32(bf, af[0][ks], acc[0][nj]);                  \
            acc[1][nj] = MFMA32(bf, af[1][ks], acc[1][nj]);                  \
        }                                                                    \
    _Pragma("unroll")                                                        \
    for (int ti = 0; ti < 2; ++ti) {                                         \
        u32 qk[4][2];                                                        \
        _Pragma("unroll")                                                    \
        for (int nj = 0; nj < 4; ++nj) {                                     \
            qk[nj][0] = pack2(acc[ti][nj][0], acc[ti][nj][1]);               \
            qk[nj][1] = pack2(acc[ti][nj][2], acc[ti][nj][3]);               \
        }                                                                    \
        union { u32 u[4]; short8 s; } q0_, q1_;                              \
        _Pragma("unroll")                                                    \
        for (int e = 0; e < 4; ++e) {                                        \
            u32 a0 = (u32)__builtin_amdgcn_ds_bpermute(adr[e], (int)qk[0][e & 1]); \
            u32 a1 = (u32)__builtin_amdgcn_ds_bpermute(adr[e], (int)qk[1][e & 1]); \
            q0_.u[e] = (lg >> 1) ? a1 : a0;                                  \
            u32 b0 = (u32)__builtin_amdgcn_ds_bpermute(adr[e], (int)qk[2][e & 1]); \
            u32 b1 = (u32)__builtin_amdgcn_ds_bpermute(adr[e], (int)qk[3][e & 1]); \
            q1_.u[e] = (lg >> 1) ? b1 : b0;                                  \
        }                                                                    \
        qf_[ti][0] = q0_.s; qf_[ti][1] = q1_.s;                              \
    }                                                                        \
    __syncthreads();   /* lk/lvT visible for attention */                    \
    } while (0)

// Grid 256: each block runs batches b and b+256 back-to-back. Batch-1's x
// loads are issued BEFORE batch-0's attention and stay in flight (128 f32
// regs) — hiding the second chip-wide x HBM burst under compute. R12 retry
// with (512,1): the (512,2) allocator clamped at 128 VGPRs and spilled;
// (512,1) releases the cap (peak live ~236 <= 256, still 2 waves/SIMD).
// Attention/projection = R18-verified. LDS = 104448 B.
__global__ __launch_bounds__(512, 1)
void attn_head_fused(const float* __restrict__ x,
                     const float* __restrict__ Wq,
                     const float* __restrict__ Wk,
                     const float* __restrict__ Wv,
                     const float* __restrict__ dmask,
                     float* __restrict__ out)
{
    __shared__ __align__(16) u16 lk[256][72];       // k [s][h]    36864 B
    __shared__ __align__(16) u16 lvT[64][264];      // v^T [h][s]  33792 B
    __shared__ __align__(16) u16 wt[64][264];       // W^T [n][c]  33792 B

    const int b0  = blockIdx.x;
    const int b1  = blockIdx.x + 256;
    const int tid = threadIdx.x;
    const int w   = tid >> 6;
    const int l   = tid & 63;
    const int lr  = l & 15;
    const int lg  = l >> 4;

    const int TbA = 16 * w;
    const int TbB = 16 * (15 - w);

    const float* xb0 = x + (size_t)b0 * 65536;
    const float* xb1 = x + (size_t)b1 * 65536;

    // bpermute transpose addresses (R10/R13/R14-verified)
    int adr[4];
    #pragma unroll
    for (int e = 0; e < 4; ++e) {
        const int lgp = ((8 * lg + 2 * e) & 15) >> 2;
        adr[e] = 4 * (lr + 16 * lgp);
    }

    f32x4 xpA[16], xpB[16];
    short8 af[2][8];
    short8 qf[2][2];

    // ================= batch 0 =================
    ISSUE_X(xpA, xb0, TbA);
    ISSUE_X(xpB, xb0, TbB);
    CVT_X(af[0], xpA);
    CVT_X(af[1], xpB);

    DO_PROJ(qf);

    // issue batch-1 x loads NOW — they stream during batch-0's attention
    ISSUE_X(xpA, xb1, TbA);
    ISSUE_X(xpB, xb1, TbB);

    attn_dual(w, 15 - w, lr, lg, adr, qf[0], qf[1], lk, lvT,
              dmask + (size_t)b0 * 65536, out + (size_t)b0 * 16384);

    __syncthreads();   // batch-0 LDS reads done before proj1 overwrites

    // ================= batch 1 =================
    CVT_X(af[0], xpA);
    CVT_X(af[1], xpB);

    DO_PROJ(qf);

    attn_dual(w, 15 - w, lr, lg, adr, qf[0], qf[1], lk, lvT,
              dmask + (size_t)b1 * 65536, out + (size_t)b1 * 16384);
}

extern "C" void kernel_launch(void* const* d_in, const int* in_sizes, int n_in,
                              void* d_out, int out_size, void* d_ws, size_t ws_size,
                              hipStream_t stream) {
    const float* x  = (const float*)d_in[0];
    const float* Wq = (const float*)d_in[1];
    const float* Wk = (const float*)d_in[2];
    const float* Wv = (const float*)d_in[3];
    const float* dm = (const float*)d_in[4];
    float* outp     = (float*)d_out;
    attn_head_fused<<<dim3(256), dim3(512), 0, stream>>>(x, Wq, Wk, Wv, dm, outp);
}

// Round 24
// 54.071 us; speedup vs baseline: 1.8666x; 1.8666x over previous
//
#include <hip/hip_runtime.h>
#include <hip/hip_bf16.h>

typedef __attribute__((ext_vector_type(8))) short short8;
typedef __attribute__((ext_vector_type(4))) float f32x4;
typedef __attribute__((ext_vector_type(4))) unsigned short ushort4v;
typedef unsigned short u16;
typedef unsigned int u32;

#define MFMA32(a, b, c) __builtin_amdgcn_mfma_f32_16x16x32_bf16((a), (b), (c), 0, 0, 0)

__device__ __forceinline__ u16 f2bf(float f) {
    __hip_bfloat16 h = __float2bfloat16(f);       // RNE; compiler can fuse pairs
    return *reinterpret_cast<u16*>(&h);
}
__device__ __forceinline__ u32 pack2(float a, float b) {
    return ((u32)f2bf(b) << 16) | (u32)f2bf(a);
}

// One 32-s chunk step for one tile — R16/R18-verified chunk body (fixed-base
// softmax exp(S/8), causal mask, dropout, bpermute PV). No conditionals
// (R17 lesson: never put MFMA accumulation under a divergent-looking guard).
// No setprio (R21: null-to-negative at 2 waves/SIMD, no role diversity).
__device__ __forceinline__ void tile_step(int c2, int t_my, int lr, int lg,
                                          const int* adr,
                                          const short8* qf,           // [2]
                                          const u16 (*lk)[72],
                                          const u16 (*lvT)[264],
                                          const float* mb,
                                          float& ls, f32x4* O)
{
    // dropout masks early (fly under QK + exp)
    f32x4 md0 = *(const f32x4*)&mb[(size_t)t_my * 256 + 32 * c2 + 4 * lg];
    f32x4 md1 = *(const f32x4*)&mb[(size_t)t_my * 256 + 32 * c2 + 16 + 4 * lg];

    // QK^T swapped: S[t=lr-col][s = 32c2 + 16sl + 4lg + j]
    f32x4 S0, S1;
    {
        const u16* kr = &lk[16 * (2 * c2) + lr][0];
        short8 kf0 = *(const short8*)&kr[8 * lg];
        short8 kf1 = *(const short8*)&kr[32 + 8 * lg];
        f32x4 a = (f32x4){0.f, 0.f, 0.f, 0.f};
        a = MFMA32(kf0, qf[0], a);
        a = MFMA32(kf1, qf[1], a);
        S0 = a;
    }
    {
        const u16* kr = &lk[16 * (2 * c2 + 1) + lr][0];
        short8 kf0 = *(const short8*)&kr[8 * lg];
        short8 kf1 = *(const short8*)&kr[32 + 8 * lg];
        f32x4 a = (f32x4){0.f, 0.f, 0.f, 0.f};
        a = MFMA32(kf0, qf[0], a);
        a = MFMA32(kf1, qf[1], a);
        S1 = a;
    }

    // exp(S/8) with causal mask; per-lane partial sum BEFORE dropout
    #pragma unroll
    for (int j = 0; j < 4; ++j) {
        const int sg0 = 32 * c2 + 4 * lg + j;
        const int sg1 = sg0 + 16;
        float p0 = exp2f(S0[j] * 0.180336879f);
        float p1 = exp2f(S1[j] * 0.180336879f);
        p0 = (sg0 <= t_my) ? p0 : 0.f;
        p1 = (sg1 <= t_my) ? p1 : 0.f;
        ls += p0 + p1;
        S0[j] = (md0[j] >= 0.25f) ? p0 : 0.f;
        S1[j] = (md1[j] >= 0.25f) ? p1 : 0.f;
    }

    // pack + lane-transpose to PV B-frag (R14-verified)
    u32 pk0[2], pk1[2];
    pk0[0] = pack2(S0[0], S0[1]); pk0[1] = pack2(S0[2], S0[3]);
    pk1[0] = pack2(S1[0], S1[1]); pk1[1] = pack2(S1[2], S1[3]);
    union { u32 u[4]; short8 s; } pf;
    #pragma unroll
    for (int e = 0; e < 4; ++e) {
        u32 ca = (u32)__builtin_amdgcn_ds_bpermute(adr[e], (int)pk0[e & 1]);
        u32 cb = (u32)__builtin_amdgcn_ds_bpermute(adr[e], (int)pk1[e & 1]);
        pf.u[e] = (lg >> 1) ? cb : ca;
    }

    #pragma unroll
    for (int ht = 0; ht < 4; ++ht) {
        short8 vf = *(const short8*)&lvT[16 * ht + lr][32 * c2 + 8 * lg];
        O[ht] = MFMA32(vf, pf.s, O[ht]);
    }
}

// Dual-tile attention, branch-free (R18-verified): loop 1 steps BOTH tiles
// (two independent dependency chains per iteration -> ILP); loop 2 finishes
// tile B alone. nchA <= 4 < 5 <= nchB always (tA = w, tB = 15-w).
__device__ __forceinline__ void attn_dual(int tA, int tB, int lr, int lg,
                                          const int* adr,
                                          const short8* qfA, const short8* qfB,
                                          const u16 (*lk)[72],
                                          const u16 (*lvT)[264],
                                          const float* mb, float* ob)
{
    const int nchA = (tA + 2) >> 1;
    const int nchB = (tB + 2) >> 1;
    const int tmA  = 16 * tA + lr;
    const int tmB  = 16 * tB + lr;

    float lsA = 0.f, lsB = 0.f;
    f32x4 OA[4], OB[4];
    #pragma unroll
    for (int ht = 0; ht < 4; ++ht) {
        OA[ht] = (f32x4){0.f, 0.f, 0.f, 0.f};
        OB[ht] = (f32x4){0.f, 0.f, 0.f, 0.f};
    }

    int c2 = 0;
    for (; c2 < nchA; ++c2) {
        tile_step(c2, tmB, lr, lg, adr, qfB, lk, lvT, mb, lsB, OB);
        tile_step(c2, tmA, lr, lg, adr, qfA, lk, lvT, mb, lsA, OA);
    }
    for (; c2 < nchB; ++c2)
        tile_step(c2, tmB, lr, lg, adr, qfB, lk, lvT, mb, lsB, OB);

    // end-of-tile row-sum reductions (lanes lr, lr+16, lr+32, lr+48 share a row)
    lsA += __shfl_xor(lsA, 16, 64);
    lsA += __shfl_xor(lsA, 32, 64);
    lsB += __shfl_xor(lsB, 16, 64);
    lsB += __shfl_xor(lsB, 32, 64);

    const float rfA = 1.33333333333f / lsA;   // (1/sum) * 1/(1-0.25)
    const float rfB = 1.33333333333f / lsB;
    #pragma unroll
    for (int ht = 0; ht < 4; ++ht) {
        f32x4 oa  = OA[ht] * rfA;
        f32x4 obv = OB[ht] * rfB;
        *(f32x4*)&ob[(size_t)tmA * 64 + 16 * ht + 4 * lg] = oa;
        *(f32x4*)&ob[(size_t)tmB * 64 + 16 * ht + 4 * lg] = obv;
    }
}

// stage full W^T bf16 into wt: lane l owns row n=l; wave w owns chunks 8(w+8i)
#define STAGE_W(Wm) do {                                                     \
    _Pragma("unroll")                                                        \
    for (int i_ = 0; i_ < 4; ++i_) {                                         \
        const int c0_ = 8 * (w + 8 * i_);                                    \
        short8 t_;                                                           \
        _Pragma("unroll")                                                    \
        for (int j_ = 0; j_ < 8; ++j_)                                       \
            t_[j_] = (short)f2bf((Wm)[(size_t)(c0_ + j_) * 64 + l]);         \
        *(short8*)&wt[l][c0_] = t_;                                          \
    } } while (0)

// FINAL (R18, best measured 54.4 us; R22 reproduction 54.4 us): one
// 512-thread block per batch; 8 waves; wave w owns t-tiles {w, 15-w} (9 PV
// chunks each, balanced). LDS W^T staging, (512,2) regime (the only one with
// healthy regalloc — R4/R5/R10/R13/R23: every other bound clamps to 64-128
// regs and spills), 5 barriers, swapped-QK^T scalar-softmax bpermute
// attention, dual-tile interleave. LDS = 104448 B.
__global__ __launch_bounds__(512, 2)
void attn_head_fused(const float* __restrict__ x,
                     const float* __restrict__ Wq,
                     const float* __restrict__ Wk,
                     const float* __restrict__ Wv,
                     const float* __restrict__ dmask,
                     float* __restrict__ out)
{
    __shared__ __align__(16) u16 lk[256][72];       // k [s][h]    36864 B
    __shared__ __align__(16) u16 lvT[64][264];      // v^T [h][s]  33792 B
    __shared__ __align__(16) u16 wt[64][264];       // W^T [n][c]  33792 B

    const int b   = blockIdx.x;
    const int tid = threadIdx.x;
    const int w   = tid >> 6;
    const int l   = tid & 63;
    const int lr  = l & 15;
    const int lg  = l >> 4;

    const int TbA = 16 * w;
    const int TbB = 16 * (15 - w);

    const float* xb = x + (size_t)b * 65536;

    // bpermute transpose addresses (R10/R13/R14-verified)
    int adr[4];
    #pragma unroll
    for (int e = 0; e < 4; ++e) {
        const int lgp = ((8 * lg + 2 * e) & 15) >> 2;
        adr[e] = 4 * (lr + 16 * lgp);
    }

    // ---- x A-fragments for both tiles (reused by all three projections) ----
    short8 af[2][8];
    #pragma unroll
    for (int ti = 0; ti < 2; ++ti) {
        const float* xr = xb + (size_t)((ti ? TbB : TbA) + lr) * 256 + lg * 8;
        #pragma unroll
        for (int ks = 0; ks < 8; ++ks) {
            f32x4 a0 = *(const f32x4*)(xr + ks * 32);
            f32x4 a1 = *(const f32x4*)(xr + ks * 32 + 4);
            short8 f;
            f[0] = (short)f2bf(a0[0]); f[1] = (short)f2bf(a0[1]);
            f[2] = (short)f2bf(a0[2]); f[3] = (short)f2bf(a0[3]);
            f[4] = (short)f2bf(a1[0]); f[5] = (short)f2bf(a1[1]);
            f[6] = (short)f2bf(a1[2]); f[7] = (short)f2bf(a1[3]);
            af[ti][ks] = f;
        }
    }

    f32x4 acc[2][4];

    // ================= k projection (normal operands) =================
    STAGE_W(Wk);
    __syncthreads();                                   // B1
    #pragma unroll
    for (int ti = 0; ti < 2; ++ti)
        #pragma unroll
        for (int nj = 0; nj < 4; ++nj) acc[ti][nj] = (f32x4){0.f,0.f,0.f,0.f};
    #pragma unroll
    for (int ks = 0; ks < 8; ++ks)
        #pragma unroll
        for (int nj = 0; nj < 4; ++nj) {
            short8 bf = *(const short8*)&wt[16 * nj + lr][ks * 32 + lg * 8];
            acc[0][nj] = MFMA32(af[0][ks], bf, acc[0][nj]);
            acc[1][nj] = MFMA32(af[1][ks], bf, acc[1][nj]);
        }
    #pragma unroll
    for (int nj = 0; nj < 4; ++nj) {
        const int n = 16 * nj + lr;
        #pragma unroll
        for (int j = 0; j < 4; ++j) {
            lk[TbA + 4 * lg + j][n] = f2bf(acc[0][nj][j]);
            lk[TbB + 4 * lg + j][n] = f2bf(acc[1][nj][j]);
        }
    }
    __syncthreads();                                   // B2 (wt readers done)

    // ================= v projection (normal operands) =================
    STAGE_W(Wv);
    __syncthreads();                                   // B3
    #pragma unroll
    for (int ti = 0; ti < 2; ++ti)
        #pragma unroll
        for (int nj = 0; nj < 4; ++nj) acc[ti][nj] = (f32x4){0.f,0.f,0.f,0.f};
    #pragma unroll
    for (int ks = 0; ks < 8; ++ks)
        #pragma unroll
        for (int nj = 0; nj < 4; ++nj) {
            short8 bf = *(const short8*)&wt[16 * nj + lr][ks * 32 + lg * 8];
            acc[0][nj] = MFMA32(af[0][ks], bf, acc[0][nj]);
            acc[1][nj] = MFMA32(af[1][ks], bf, acc[1][nj]);
        }
    #pragma unroll
    for (int ti = 0; ti < 2; ++ti) {
        const int s0 = (ti ? TbB : TbA) + 4 * lg;
        #pragma unroll
        for (int nj = 0; nj < 4; ++nj) {
            ushort4v pk;
            pk[0] = f2bf(acc[ti][nj][0]);
            pk[1] = f2bf(acc[ti][nj][1]);
            pk[2] = f2bf(acc[ti][nj][2]);
            pk[3] = f2bf(acc[ti][nj][3]);
            *(ushort4v*)&lvT[16 * nj + lr][s0] = pk;
        }
    }
    __syncthreads();                                   // B4 (wt readers done)

    // ========== q projection (SWAPPED -> per-lane q rows -> bpermute B-frags) ==========
    STAGE_W(Wq);
    __syncthreads();                                   // B5 (also: lk/lvT visible)
    #pragma unroll
    for (int ti = 0; ti < 2; ++ti)
        #pragma unroll
        for (int nj = 0; nj < 4; ++nj) acc[ti][nj] = (f32x4){0.f,0.f,0.f,0.f};
    #pragma unroll
    for (int ks = 0; ks < 8; ++ks)
        #pragma unroll
        for (int nj = 0; nj < 4; ++nj) {
            short8 bf = *(const short8*)&wt[16 * nj + lr][ks * 32 + lg * 8];
            acc[0][nj] = MFMA32(bf, af[0][ks], acc[0][nj]);   // A=W^T, B=x
            acc[1][nj] = MFMA32(bf, af[1][ks], acc[1][nj]);
        }
    short8 qf[2][2];
    #pragma unroll
    for (int ti = 0; ti < 2; ++ti) {
        u32 qk[4][2];
        #pragma unroll
        for (int nj = 0; nj < 4; ++nj) {
            qk[nj][0] = pack2(acc[ti][nj][0], acc[ti][nj][1]);
            qk[nj][1] = pack2(acc[ti][nj][2], acc[ti][nj][3]);
        }
        union { u32 u[4]; short8 s; } q0, q1;
        #pragma unroll
        for (int e = 0; e < 4; ++e) {
            u32 a0 = (u32)__builtin_amdgcn_ds_bpermute(adr[e], (int)qk[0][e & 1]);
            u32 a1 = (u32)__builtin_amdgcn_ds_bpermute(adr[e], (int)qk[1][e & 1]);
            q0.u[e] = (lg >> 1) ? a1 : a0;
            u32 b0 = (u32)__builtin_amdgcn_ds_bpermute(adr[e], (int)qk[2][e & 1]);
            u32 b1 = (u32)__builtin_amdgcn_ds_bpermute(adr[e], (int)qk[3][e & 1]);
            q1.u[e] = (lg >> 1) ? b1 : b0;
        }
        qf[ti][0] = q0.s; qf[ti][1] = q1.s;
    }

    // ========== attention: dual-tile, branch-free, barrier-free ==========
    const float* mb = dmask + (size_t)b * 65536;
    float* ob = out + (size_t)b * 16384;

    attn_dual(w, 15 - w, lr, lg, adr, qf[0], qf[1], lk, lvT, mb, ob);
}

extern "C" void kernel_launch(void* const* d_in, const int* in_sizes, int n_in,
                              void* d_out, int out_size, void* d_ws, size_t ws_size,
                              hipStream_t stream) {
    const float* x  = (const float*)d_in[0];
    const float* Wq = (const float*)d_in[1];
    const float* Wk = (const float*)d_in[2];
    const float* Wv = (const float*)d_in[3];
    const float* dm = (const float*)d_in[4];
    float* outp     = (float*)d_out;
    attn_head_fused<<<dim3(512), dim3(512), 0, stream>>>(x, Wq, Wk, Wv, dm, outp);
}